// Round 11
// baseline (866.675 us; speedup 1.0000x reference)
//
#include <hip/hip_runtime.h>
#include <hip/hip_bf16.h>
#include <math.h>

#define BN_EPS 1e-5f
#define CAP 6144          // bucket capacity (mean 4092 for E=1.6M, nb=391)
#define MAXB 512          // max coarse buckets supported

typedef __attribute__((ext_vector_type(8))) short short8;
typedef __attribute__((ext_vector_type(4))) float floatx4;

__device__ inline float4 ntload4(const float* p) {
    floatx4 v = __builtin_nontemporal_load((const floatx4*)p);
    return make_float4(v.x, v.y, v.z, v.w);
}

// ---------------- prep: Wf1 = frag(proj_W@W1), bc = proj_b@W1, Wf2 = frag(W2),
//                  bcursor + bn-counter init. ----------------
__global__ __launch_bounds__(128) void prep_kernel(
    const float* __restrict__ PW, const float* __restrict__ W1,
    const float* __restrict__ pb, const float* __restrict__ W2,
    __hip_bfloat16* __restrict__ Wf1, __hip_bfloat16* __restrict__ Wf2,
    float* __restrict__ bc, int* __restrict__ bcursor, int nb)
{
    int bid = blockIdx.x;
    int tid = threadIdx.x;
    if (bid < 256) {                 // Wc row k -> Wf1 fragment order (4-way ILP)
        int k = bid, c = tid;
        float a0 = 0.f, a1 = 0.f, a2 = 0.f, a3 = 0.f;
        for (int kk = 0; kk < 256; kk += 4) {
            a0 = fmaf(PW[k * 256 + kk],     W1[(kk)     * 128 + c], a0);
            a1 = fmaf(PW[k * 256 + kk + 1], W1[(kk + 1) * 128 + c], a1);
            a2 = fmaf(PW[k * 256 + kk + 2], W1[(kk + 2) * 128 + c], a2);
            a3 = fmaf(PW[k * 256 + kk + 3], W1[(kk + 3) * 128 + c], a3);
        }
        float acc = (a0 + a1) + (a2 + a3);
        int kc = k >> 5, r5 = k & 31, qq = r5 >> 3, j = r5 & 7;
        int ct = c >> 4, l16 = c & 15;
        int lane = qq * 16 + l16;
        Wf1[(((kc * 8 + ct) * 64) + lane) * 8 + j] = __float2bfloat16(acc);
    } else if (bid == 256) {         // bc
        int c = tid;
        float a0 = 0.f, a1 = 0.f, a2 = 0.f, a3 = 0.f;
        for (int k = 0; k < 256; k += 4) {
            a0 = fmaf(pb[k],     W1[(k)     * 128 + c], a0);
            a1 = fmaf(pb[k + 1], W1[(k + 1) * 128 + c], a1);
            a2 = fmaf(pb[k + 2], W1[(k + 2) * 128 + c], a2);
            a3 = fmaf(pb[k + 3], W1[(k + 3) * 128 + c], a3);
        }
        bc[c] = (a0 + a1) + (a2 + a3);
    } else if (bid < 385) {          // Wf2 pack (K=128): 16384 elems
        int t = (bid - 257) * 128 + tid;
        int j    = t & 7;
        int lane = (t >> 3) & 63;
        int ct   = (t >> 9) & 7;
        int kc   = t >> 12;
        int k = kc * 32 + ((lane >> 4) & 3) * 8 + j;
        int c = ct * 16 + (lane & 15);
        Wf2[t] = __float2bfloat16(W2[k * 128 + c]);
    } else {                          // bcursor + bn-final counter init
        int i = (bid - 385) * 128 + tid;
        if (i < nb) bcursor[i] = i * CAP;
        if (bid == 385 && tid < 2) bcursor[nb + 8 + tid] = 0;   // bn ctrs
    }
}

// ---------------- bucket scatter body (bucket = dst>>8), device fn ----------
__device__ void bucket_body(
    const int* __restrict__ src, const int* __restrict__ dst,
    int* __restrict__ bcursor, unsigned* __restrict__ buck,
    int E, int nb, int nblocks, int bid)
{
    __shared__ int h[MAXB], resv[MAXB], cur[MAXB];
    for (int t = threadIdx.x; t < nb; t += 256) { h[t] = 0; cur[t] = 0; }
    __syncthreads();
    int per = (E + nblocks - 1) / nblocks;
    int e0 = bid * per;
    int e1 = min(e0 + per, E);
    for (int e = e0 + threadIdx.x; e < e1; e += 256) {
        int d = dst[e];
        atomicAdd(&h[d >> 8], 1);
    }
    __syncthreads();
    for (int t = threadIdx.x; t < nb; t += 256) {
        int c = h[t];
        if (c > 0) resv[t] = atomicAdd(&bcursor[t], c);
    }
    __syncthreads();
    for (int e = e0 + threadIdx.x; e < e1; e += 256) {
        int d = dst[e];
        int s = src[e];
        int b = d >> 8;
        int pos = resv[b] + atomicAdd(&cur[b], 1);
        buck[pos] = ((unsigned)(d & 255) << 17) | (unsigned)s;   // src < 2^17
    }
}

__device__ inline uint2 scale_u2(uint2 v, float d) {
    float f0 = __uint_as_float(v.x << 16) * d;
    float f1 = __uint_as_float(v.x & 0xffff0000u) * d;
    float f2 = __uint_as_float(v.y << 16) * d;
    float f3 = __uint_as_float(v.y & 0xffff0000u) * d;
    __hip_bfloat162 p0 = __float22bfloat162_rn(make_float2(f0, f1));
    __hip_bfloat162 p1 = __float22bfloat162_rn(make_float2(f2, f3));
    uint2 o;
    o.x = *(unsigned*)&p0;
    o.y = *(unsigned*)&p1;
    return o;
}

// ---------------- kernel B: per-bucket exact CSR build (+inline prefix)
// + in-place dinv scaling of this bucket's Hs rows (slice-major layout). ----
__global__ __launch_bounds__(256) void csr_kernel(
    const unsigned* __restrict__ buck, const int* __restrict__ bcursor,
    int* __restrict__ cnt, int* __restrict__ rowptr, float* __restrict__ dinv,
    int* __restrict__ ssrc, uint2* __restrict__ HU, int N)
{
    __shared__ int h[256], sc[256], lcur[256], redu[256];
    __shared__ float sdv[256];
    int b = blockIdx.x;
    int t = threadIdx.x;
    int part = 0;
    for (int i = t; i < b; i += 256) part += bcursor[i] - i * CAP;
    redu[t] = part;
    h[t] = 0;
    __syncthreads();
    for (int off = 128; off > 0; off >>= 1) {
        if (t < off) redu[t] += redu[t + off];
        __syncthreads();
    }
    int cb = redu[0];

    int base = b * CAP;
    int nB = bcursor[b] - base;
    for (int i = t; i < nB; i += 256) {
        unsigned v = buck[base + i];
        atomicAdd(&h[v >> 17], 1);
    }
    __syncthreads();
    int myc = h[t];
    sc[t] = myc;
    __syncthreads();
    for (int off = 1; off < 256; off <<= 1) {
        int x = (t >= off) ? sc[t - off] : 0;
        __syncthreads();
        sc[t] += x;
        __syncthreads();
    }
    int ex = sc[t] - myc;
    lcur[t] = ex;
    int node = b * 256 + t;
    float dv = rsqrtf((float)myc + 1.0f);
    sdv[t] = dv;
    if (node < N) {
        cnt[node]    = myc;
        rowptr[node] = cb + ex;
        dinv[node]   = dv;
    }
    __syncthreads();
    for (int i = t; i < nB; i += 256) {
        unsigned v = buck[base + i];
        int dloc = v >> 17;
        int pos = cb + atomicAdd(&lcur[dloc], 1);
        ssrc[pos] = (int)(v & 0x1FFFFu);
    }
    // ---- scale Hs rows of this bucket by dinv, slice-major layout:
    //      HU[((s*N + row) * 4 + u] (uint2 = 4 bf16). Coalesced per slice. ----
    int rbase = b * 256;
    int nrow  = min(256, N - rbase);
    for (int s2 = 0; s2 < 8; ++s2) {
        for (int i = t; i < nrow * 4; i += 256) {
            int row = i >> 2;
            int uu  = i & 3;
            size_t a = ((size_t)s2 * N + rbase + row) * 4 + uu;
            HU[a] = scale_u2(HU[a], sdv[row]);
        }
    }
}

__device__ inline short8 cvt8(float4 a, float4 b) {
    __hip_bfloat162 p0 = __float22bfloat162_rn(make_float2(a.x, a.y));
    __hip_bfloat162 p1 = __float22bfloat162_rn(make_float2(a.z, a.w));
    __hip_bfloat162 p2 = __float22bfloat162_rn(make_float2(b.x, b.y));
    __hip_bfloat162 p3 = __float22bfloat162_rn(make_float2(b.z, b.w));
    union { short8 s; __hip_bfloat162 h[4]; } u;
    u.h[0] = p0; u.h[1] = p1; u.h[2] = p2; u.h[3] = p3;
    return u.s;
}

// ---------------- MFMA GEMM body: Hs(bf16) = (op(X)@W + bias) [* dinv] ------
// Hs is SLICE-MAJOR: element (row, c) at Hs[(ct*N + row)*16 + l16], ct=c/16.
template <int K, bool BN, bool DINV>
__device__ void gemm_body(
    int bid,
    const float* __restrict__ X, const short* __restrict__ Wf,
    const float* __restrict__ bias, const float* __restrict__ dinv,
    const float* __restrict__ scale, const float* __restrict__ shift,
    __hip_bfloat16* __restrict__ Hs, int N)
{
    const int wave = threadIdx.x >> 6;
    const int lane = threadIdx.x & 63;
    const int l16  = lane & 15;
    const int q    = lane >> 4;            // 0..3
    const int r0   = bid * 128 + wave * 32;

    const int ra0 = min(r0 + l16, N - 1);
    const int ra1 = min(r0 + 16 + l16, N - 1);
    const float* pA0 = X + (size_t)ra0 * K + q * 8;
    const float* pA1 = X + (size_t)ra1 * K + q * 8;
    const short8* WF = (const short8*)Wf;

    floatx4 acc[2][8];
#pragma unroll
    for (int rt = 0; rt < 2; ++rt)
#pragma unroll
        for (int ct = 0; ct < 8; ++ct) { acc[rt][ct][0] = 0.f; acc[rt][ct][1] = 0.f; acc[rt][ct][2] = 0.f; acc[rt][ct][3] = 0.f; }

#pragma unroll
    for (int kc = 0; kc < K / 32; ++kc) {
        short8 b[8];
#pragma unroll
        for (int ct = 0; ct < 8; ++ct) b[ct] = WF[(kc * 8 + ct) * 64 + lane];

        float4 x00 = ntload4(pA0 + kc * 32);
        float4 x01 = ntload4(pA0 + kc * 32 + 4);
        float4 x10 = ntload4(pA1 + kc * 32);
        float4 x11 = ntload4(pA1 + kc * 32 + 4);
        if (BN) {
            float4 sc0 = *(const float4*)(scale + kc * 32 + q * 8);
            float4 sc1 = *(const float4*)(scale + kc * 32 + q * 8 + 4);
            float4 sh0 = *(const float4*)(shift + kc * 32 + q * 8);
            float4 sh1 = *(const float4*)(shift + kc * 32 + q * 8 + 4);
            x00.x = fmaxf(fmaf(x00.x, sc0.x, sh0.x), 0.f);
            x00.y = fmaxf(fmaf(x00.y, sc0.y, sh0.y), 0.f);
            x00.z = fmaxf(fmaf(x00.z, sc0.z, sh0.z), 0.f);
            x00.w = fmaxf(fmaf(x00.w, sc0.w, sh0.w), 0.f);
            x01.x = fmaxf(fmaf(x01.x, sc1.x, sh1.x), 0.f);
            x01.y = fmaxf(fmaf(x01.y, sc1.y, sh1.y), 0.f);
            x01.z = fmaxf(fmaf(x01.z, sc1.z, sh1.z), 0.f);
            x01.w = fmaxf(fmaf(x01.w, sc1.w, sh1.w), 0.f);
            x10.x = fmaxf(fmaf(x10.x, sc0.x, sh0.x), 0.f);
            x10.y = fmaxf(fmaf(x10.y, sc0.y, sh0.y), 0.f);
            x10.z = fmaxf(fmaf(x10.z, sc0.z, sh0.z), 0.f);
            x10.w = fmaxf(fmaf(x10.w, sc0.w, sh0.w), 0.f);
            x11.x = fmaxf(fmaf(x11.x, sc1.x, sh1.x), 0.f);
            x11.y = fmaxf(fmaf(x11.y, sc1.y, sh1.y), 0.f);
            x11.z = fmaxf(fmaf(x11.z, sc1.z, sh1.z), 0.f);
            x11.w = fmaxf(fmaf(x11.w, sc1.w, sh1.w), 0.f);
        }
        short8 a0 = cvt8(x00, x01);
        short8 a1 = cvt8(x10, x11);
#pragma unroll
        for (int ct = 0; ct < 8; ++ct) {
            acc[0][ct] = __builtin_amdgcn_mfma_f32_16x16x32_bf16(a0, b[ct], acc[0][ct], 0, 0, 0);
            acc[1][ct] = __builtin_amdgcn_mfma_f32_16x16x32_bf16(a1, b[ct], acc[1][ct], 0, 0, 0);
        }
    }

    float bb[8];
#pragma unroll
    for (int ct = 0; ct < 8; ++ct) bb[ct] = bias ? bias[ct * 16 + l16] : 0.f;

#pragma unroll
    for (int rt = 0; rt < 2; ++rt) {
        int rbase = r0 + rt * 16 + q * 4;
        float dv[4];
#pragma unroll
        for (int i = 0; i < 4; ++i) dv[i] = DINV ? dinv[min(rbase + i, N - 1)] : 1.f;
#pragma unroll
        for (int ct = 0; ct < 8; ++ct) {
#pragma unroll
            for (int i = 0; i < 4; ++i) {
                int row = rbase + i;
                if (row < N)
                    Hs[((size_t)ct * N + row) * 16 + l16] =
                        __float2bfloat16(DINV ? (acc[rt][ct][i] + bb[ct]) * dv[i]
                                              : (acc[rt][ct][i] + bb[ct]));
            }
        }
    }
}

// ---------------- merged launch: gemm1 + bucket, SEQUENTIAL role map ---------
// r9 lesson: interleaved map with two gemm_body call sites inflated VGPR
// 80->156 (occupancy 24%->8%, 86->130us). Keep ONE call site per body.
__global__ __launch_bounds__(256) void gemm1_bucket_kernel(
    const float* __restrict__ X, const short* __restrict__ Wf,
    const float* __restrict__ bias,
    __hip_bfloat16* __restrict__ Hs, int N, int gemmGrid,
    const int* __restrict__ src, const int* __restrict__ dst,
    int* __restrict__ bcursor, unsigned* __restrict__ buck, int E, int nb,
    int bucketGrid)
{
    if ((int)blockIdx.x < gemmGrid)
        gemm_body<256, false, false>(blockIdx.x, X, Wf, bias, nullptr, nullptr, nullptr, Hs, N);
    else
        bucket_body(src, dst, bcursor, buck, E, nb, bucketGrid,
                    (int)blockIdx.x - gemmGrid);
}

__global__ __launch_bounds__(256) void mfma_gemm2_kernel(
    const float* __restrict__ X, const short* __restrict__ Wf,
    const float* __restrict__ dinv,
    const float* __restrict__ scale, const float* __restrict__ shift,
    __hip_bfloat16* __restrict__ Hs, int N)
{
    gemm_body<128, true, true>(blockIdx.x, X, Wf, nullptr, dinv, scale, shift, Hs, N);
}

// ---------------- gather-reduce aggregation, SLICE-MAJOR + XCD-matched -------
// Hs layout [8][N][16 bf16]: slice s is a contiguous 3.2MB region that fits
// one XCD's 4MB L2. Block bid handles slice bid&7; dispatch round-robins
// bid%8 -> XCD, so each XCD's gathers hit only its own L2-resident slice.
// 4-lane groups x 16 edges/wave; uint2 (4 bf16) per lane; 4 nodes/wave.
__global__ __launch_bounds__(256) void agg_gather_kernel(
    const uint2* __restrict__ HU, const int* __restrict__ rowptr,
    const int* __restrict__ cnt, const int* __restrict__ ssrc,
    const float* __restrict__ dinv, const float* __restrict__ bias,
    float* __restrict__ Out, int N)
{
    const int s        = blockIdx.x & 7;
    const int nodeBase = (blockIdx.x >> 3) * 16;
    const int w        = threadIdx.x >> 6;
    const int lane     = threadIdx.x & 63;
    const int g        = lane >> 2;      // edge group 0..15
    const int u        = lane & 3;       // uint2 within 32B row-slice
    const size_t sliceOff = (size_t)s * N;

    const float4 bb = *(const float4*)(bias + s * 16 + u * 4);

#pragma unroll
    for (int nn = 0; nn < 4; ++nn) {
        int n = nodeBase + w * 4 + nn;
        if (n < N) {
            float a0 = 0.f, a1 = 0.f, a2 = 0.f, a3 = 0.f;
            if (g == 0) {                 // self term (pre-scaled by dinv)
                uint2 v = HU[(sliceOff + n) * 4 + u];
                a0 += __uint_as_float(v.x << 16);
                a1 += __uint_as_float(v.x & 0xffff0000u);
                a2 += __uint_as_float(v.y << 16);
                a3 += __uint_as_float(v.y & 0xffff0000u);
            }
            int start = rowptr[n];
            int num   = cnt[n];
            for (int j = g; j < num; j += 16) {
                int sidx = ssrc[start + j];
                uint2 v = HU[(sliceOff + sidx) * 4 + u];
                a0 += __uint_as_float(v.x << 16);
                a1 += __uint_as_float(v.x & 0xffff0000u);
                a2 += __uint_as_float(v.y << 16);
                a3 += __uint_as_float(v.y & 0xffff0000u);
            }
            // reduce across the 16 groups (stride-4 lanes)
            for (int off = 4; off < 64; off <<= 1) {
                a0 += __shfl_xor(a0, off, 64);
                a1 += __shfl_xor(a1, off, 64);
                a2 += __shfl_xor(a2, off, 64);
                a3 += __shfl_xor(a3, off, 64);
            }
            if (g == 0) {
                float di = dinv[n];
                float4 o;
                o.x = fmaf(a0, di, bb.x);
                o.y = fmaf(a1, di, bb.y);
                o.z = fmaf(a2, di, bb.z);
                o.w = fmaf(a3, di, bb.w);
                *(float4*)(Out + (size_t)n * 128 + s * 16 + u * 4) = o;
            }
        }
    }
}

// ---------------- BN stats: partials + fused LAST-BLOCK finalize -------------
// The only viable in-kernel sync on this chip (r5 spin 93us, r7 spin 360us):
// nobody waits; the last arriving block does the finalize.
__global__ __launch_bounds__(256) void bn_stats_kernel(
    const float* __restrict__ A, float* __restrict__ partS, float* __restrict__ partQ,
    int N, int R,
    const float* __restrict__ gamma, const float* __restrict__ beta,
    float* __restrict__ scale, float* __restrict__ shift, int* __restrict__ ctr)
{
    int col4   = threadIdx.x & 31;
    int rowoff = threadIdx.x >> 5;
    int r0 = blockIdx.x * R;
    int r1 = min(r0 + R, N);
    float4 s = make_float4(0.f, 0.f, 0.f, 0.f);
    float4 qq = make_float4(0.f, 0.f, 0.f, 0.f);
#pragma unroll 4
    for (int r = r0 + rowoff; r < r1; r += 8) {
        float4 v = *(const float4*)&A[(size_t)r * 128 + col4 * 4];
        s.x += v.x; s.y += v.y; s.z += v.z; s.w += v.w;
        qq.x = fmaf(v.x, v.x, qq.x);
        qq.y = fmaf(v.y, v.y, qq.y);
        qq.z = fmaf(v.z, v.z, qq.z);
        qq.w = fmaf(v.w, v.w, qq.w);
    }
    __shared__ float4 ls[256], lq[256];
    ls[threadIdx.x] = s;
    lq[threadIdx.x] = qq;
    __syncthreads();
    if (threadIdx.x < 32) {
        float4 ts = ls[threadIdx.x], tq = lq[threadIdx.x];
#pragma unroll
        for (int k = 1; k < 8; ++k) {
            float4 xs = ls[k * 32 + threadIdx.x];
            float4 xq = lq[k * 32 + threadIdx.x];
            ts.x += xs.x; ts.y += xs.y; ts.z += xs.z; ts.w += xs.w;
            tq.x += xq.x; tq.y += xq.y; tq.z += xq.z; tq.w += xq.w;
        }
        *(float4*)&partS[(size_t)blockIdx.x * 128 + threadIdx.x * 4] = ts;
        *(float4*)&partQ[(size_t)blockIdx.x * 128 + threadIdx.x * 4] = tq;
    }
    __syncthreads();
    __shared__ int amLast;
    if (threadIdx.x == 0) {
        __threadfence();
        amLast = (atomicAdd(ctr, 1) == (int)gridDim.x - 1);
    }
    __syncthreads();
    if (!amLast) return;
    __threadfence();
    int c = threadIdx.x & 127;
    int h = threadIdx.x >> 7;
    float fs = 0.f, fq = 0.f;
    for (int b = h * 128; b < h * 128 + 128; ++b) {
        fs += partS[(size_t)b * 128 + c];
        fq += partQ[(size_t)b * 128 + c];
    }
    __shared__ float rs_[256], rq_[256];
    rs_[threadIdx.x] = fs;
    rq_[threadIdx.x] = fq;
    __syncthreads();
    if (threadIdx.x < 128) {
        float S = rs_[threadIdx.x] + rs_[threadIdx.x + 128];
        float Q = rq_[threadIdx.x] + rq_[threadIdx.x + 128];
        float m = S / (float)N;
        float v = Q / (float)N - m * m;
        float rs = rsqrtf(v + BN_EPS);
        float sc = gamma[c] * rs;
        scale[c] = sc;
        shift[c] = fmaf(-m, sc, beta[c]);
    }
}

// ---------------- final BN apply in-place on d_out (scale/shift form) --------
__global__ void bn_apply_kernel(float* __restrict__ A, const float* __restrict__ scale,
                                const float* __restrict__ shift, int N) {
    int i = blockIdx.x * blockDim.x + threadIdx.x;   // float4 index
    if (i >= N * 32) return;
    int c4 = i & 31;
    float4 v  = ((float4*)A)[i];
    float4 sc = ((const float4*)scale)[c4];
    float4 sh = ((const float4*)shift)[c4];
    v.x = fmaf(v.x, sc.x, sh.x);
    v.y = fmaf(v.y, sc.y, sh.y);
    v.z = fmaf(v.z, sc.z, sh.z);
    v.w = fmaf(v.w, sc.w, sh.w);
    ((float4*)A)[i] = v;
}

extern "C" void kernel_launch(void* const* d_in, const int* in_sizes, int n_in,
                              void* d_out, int out_size, void* d_ws, size_t ws_size,
                              hipStream_t stream) {
    const float* e_prev = (const float*)d_in[0];
    const int*   edges  = (const int*)d_in[1];
    const float* proj_W = (const float*)d_in[2];
    const float* proj_b = (const float*)d_in[3];
    const float* W1     = (const float*)d_in[4];
    const float* b1     = (const float*)d_in[5];
    const float* gamma1 = (const float*)d_in[6];
    const float* beta1  = (const float*)d_in[7];
    const float* W2     = (const float*)d_in[8];
    const float* b2     = (const float*)d_in[9];
    const float* gamma2 = (const float*)d_in[10];
    const float* beta2  = (const float*)d_in[11];
    float* out = (float*)d_out;

    const int N = in_sizes[0] / 256;
    const int E = in_sizes[1] / 2;
    const int* src = edges;
    const int* dst = edges + E;
    const int nb = (N + 255) >> 8;   // coarse buckets (391 for N=100k)
    const int R = (N + 255) / 256;   // rows per bn-stats block

    char* p = (char*)d_ws;
    const size_t NH = (size_t)N * 128;
    __hip_bfloat16* Hs = (__hip_bfloat16*)p;  p += NH * 2;
    unsigned* buck  = (unsigned*)p; p += (size_t)nb * CAP * 4;
    int* ssrc   = (int*)p;  p += (size_t)E * 4;
    int* cnt    = (int*)p;  p += (size_t)N * 4;
    int* rowptr = (int*)p;  p += (size_t)N * 4;
    float* dinv = (float*)p; p += (size_t)N * 4;
    int* bcursor = (int*)p; p += (size_t)(nb + 16) * 4;
    float* bc   = (float*)p; p += 128 * 4;
    float* stats = (float*)p; p += 1536 * 4;
    float* partS = (float*)p; p += 256 * 128 * 4;
    float* partQ = (float*)p; p += 256 * 128 * 4;
    __hip_bfloat16* Wf1 = (__hip_bfloat16*)p; p += 256 * 128 * 2;
    __hip_bfloat16* Wf2 = (__hip_bfloat16*)p; p += 128 * 128 * 2;
    float* scale1 = stats, *shift1 = stats + 128;
    float* scale2 = stats + 256, *shift2 = stats + 384;
    int* ctr1 = bcursor + nb + 8;
    int* ctr2 = bcursor + nb + 9;

    const int gemm_grid = (N + 127) / 128;
    const int bucket_grid = 512;
    const int agg_grid = ((N + 15) / 16) * 8;   // chunks x 8 slices

    // 1. prep (weights pack + bcursor/ctr init)
    prep_kernel<<<389, 128, 0, stream>>>(proj_W, W1, proj_b, W2, Wf1, Wf2, bc, bcursor, nb);
    // 2. gemm1 (unscaled slice-major Hs) + bucket, merged (sequential map)
    gemm1_bucket_kernel<<<gemm_grid + bucket_grid, 256, 0, stream>>>(
        e_prev, (const short*)Wf1, bc, Hs, N, gemm_grid,
        src, dst, bcursor, buck, E, nb, bucket_grid);
    // 3. CSR build + in-place dinv scaling of Hs (slice-major)
    csr_kernel<<<nb, 256, 0, stream>>>(buck, bcursor, cnt, rowptr, dinv, ssrc,
                                       (uint2*)Hs, N);
    // 4. layer-1 aggregation (slice-major, XCD-matched)
    agg_gather_kernel<<<agg_grid, 256, 0, stream>>>(
        (const uint2*)Hs, rowptr, cnt, ssrc, dinv, b1, out, N);
    // 5. BN1 stats (last-block finalize -> scale1/shift1)
    bn_stats_kernel<<<256, 256, 0, stream>>>(out, partS, partQ, N, R,
                                             gamma1, beta1, scale1, shift1, ctr1);
    // 6. layer-2 GEMM (BN1+relu on the fly, dinv epilogue, slice-major Hs)
    mfma_gemm2_kernel<<<gemm_grid, 256, 0, stream>>>(
        out, (const short*)Wf2, dinv, scale1, shift1, Hs, N);
    // 7. layer-2 aggregation
    agg_gather_kernel<<<agg_grid, 256, 0, stream>>>(
        (const uint2*)Hs, rowptr, cnt, ssrc, dinv, b2, out, N);
    // 8. BN2 stats (last-block finalize -> scale2/shift2)
    bn_stats_kernel<<<256, 256, 0, stream>>>(out, partS, partQ, N, R,
                                             gamma2, beta2, scale2, shift2, ctr2);
    // 9. BN2 apply
    bn_apply_kernel<<<(N * 32 + 255) / 256, 256, 0, stream>>>(out, scale2, shift2, N);
}

// Round 12
// 557.850 us; speedup vs baseline: 1.5536x; 1.5536x over previous
//
#include <hip/hip_runtime.h>
#include <hip/hip_bf16.h>
#include <math.h>

#define BN_EPS 1e-5f
#define CAP 6144          // bucket capacity (mean 4092 for E=1.6M, nb=391)
#define MAXB 512          // max coarse buckets supported

typedef __attribute__((ext_vector_type(8))) short short8;
typedef __attribute__((ext_vector_type(4))) float floatx4;

__device__ inline float4 ntload4(const float* p) {
    floatx4 v = __builtin_nontemporal_load((const floatx4*)p);
    return make_float4(v.x, v.y, v.z, v.w);
}

// ---------------- prep: Wf1 = frag(proj_W@W1), bc = proj_b@W1, Wf2 = frag(W2),
//                  bcursor + bn-counter init. ----------------
__global__ __launch_bounds__(128) void prep_kernel(
    const float* __restrict__ PW, const float* __restrict__ W1,
    const float* __restrict__ pb, const float* __restrict__ W2,
    __hip_bfloat16* __restrict__ Wf1, __hip_bfloat16* __restrict__ Wf2,
    float* __restrict__ bc, int* __restrict__ bcursor, int nb)
{
    int bid = blockIdx.x;
    int tid = threadIdx.x;
    if (bid < 256) {                 // Wc row k -> Wf1 fragment order (4-way ILP)
        int k = bid, c = tid;
        float a0 = 0.f, a1 = 0.f, a2 = 0.f, a3 = 0.f;
        for (int kk = 0; kk < 256; kk += 4) {
            a0 = fmaf(PW[k * 256 + kk],     W1[(kk)     * 128 + c], a0);
            a1 = fmaf(PW[k * 256 + kk + 1], W1[(kk + 1) * 128 + c], a1);
            a2 = fmaf(PW[k * 256 + kk + 2], W1[(kk + 2) * 128 + c], a2);
            a3 = fmaf(PW[k * 256 + kk + 3], W1[(kk + 3) * 128 + c], a3);
        }
        float acc = (a0 + a1) + (a2 + a3);
        int kc = k >> 5, r5 = k & 31, qq = r5 >> 3, j = r5 & 7;
        int ct = c >> 4, l16 = c & 15;
        int lane = qq * 16 + l16;
        Wf1[(((kc * 8 + ct) * 64) + lane) * 8 + j] = __float2bfloat16(acc);
    } else if (bid == 256) {         // bc
        int c = tid;
        float a0 = 0.f, a1 = 0.f, a2 = 0.f, a3 = 0.f;
        for (int k = 0; k < 256; k += 4) {
            a0 = fmaf(pb[k],     W1[(k)     * 128 + c], a0);
            a1 = fmaf(pb[k + 1], W1[(k + 1) * 128 + c], a1);
            a2 = fmaf(pb[k + 2], W1[(k + 2) * 128 + c], a2);
            a3 = fmaf(pb[k + 3], W1[(k + 3) * 128 + c], a3);
        }
        bc[c] = (a0 + a1) + (a2 + a3);
    } else if (bid < 385) {          // Wf2 pack (K=128): 16384 elems
        int t = (bid - 257) * 128 + tid;
        int j    = t & 7;
        int lane = (t >> 3) & 63;
        int ct   = (t >> 9) & 7;
        int kc   = t >> 12;
        int k = kc * 32 + ((lane >> 4) & 3) * 8 + j;
        int c = ct * 16 + (lane & 15);
        Wf2[t] = __float2bfloat16(W2[k * 128 + c]);
    } else {                          // bcursor + bn-final counter init
        int i = (bid - 385) * 128 + tid;
        if (i < nb) bcursor[i] = i * CAP;
        if (bid == 385 && tid < 2) bcursor[nb + 8 + tid] = 0;   // bn ctrs
    }
}

// ---------------- bucket scatter body (bucket = dst>>8), device fn ----------
__device__ void bucket_body(
    const int* __restrict__ src, const int* __restrict__ dst,
    int* __restrict__ bcursor, unsigned* __restrict__ buck,
    int E, int nb, int nblocks, int bid)
{
    __shared__ int h[MAXB], resv[MAXB], cur[MAXB];
    for (int t = threadIdx.x; t < nb; t += 256) { h[t] = 0; cur[t] = 0; }
    __syncthreads();
    int per = (E + nblocks - 1) / nblocks;
    int e0 = bid * per;
    int e1 = min(e0 + per, E);
    for (int e = e0 + threadIdx.x; e < e1; e += 256) {
        int d = dst[e];
        atomicAdd(&h[d >> 8], 1);
    }
    __syncthreads();
    for (int t = threadIdx.x; t < nb; t += 256) {
        int c = h[t];
        if (c > 0) resv[t] = atomicAdd(&bcursor[t], c);
    }
    __syncthreads();
    for (int e = e0 + threadIdx.x; e < e1; e += 256) {
        int d = dst[e];
        int s = src[e];
        int b = d >> 8;
        int pos = resv[b] + atomicAdd(&cur[b], 1);
        buck[pos] = ((unsigned)(d & 255) << 17) | (unsigned)s;   // src < 2^17
    }
}

// ---------------- kernel B: per-bucket exact CSR build (+inline prefix)
// + in-place dinv scaling of this bucket's Hs rows (row-major). ----
__global__ __launch_bounds__(256) void csr_kernel(
    const unsigned* __restrict__ buck, const int* __restrict__ bcursor,
    int* __restrict__ cnt, int* __restrict__ rowptr, float* __restrict__ dinv,
    int* __restrict__ ssrc, uint4* __restrict__ Hq, int N)
{
    __shared__ int h[256], sc[256], lcur[256], redu[256];
    __shared__ float sdv[256];
    int b = blockIdx.x;
    int t = threadIdx.x;
    int part = 0;
    for (int i = t; i < b; i += 256) part += bcursor[i] - i * CAP;
    redu[t] = part;
    h[t] = 0;
    __syncthreads();
    for (int off = 128; off > 0; off >>= 1) {
        if (t < off) redu[t] += redu[t + off];
        __syncthreads();
    }
    int cb = redu[0];

    int base = b * CAP;
    int nB = bcursor[b] - base;
    for (int i = t; i < nB; i += 256) {
        unsigned v = buck[base + i];
        atomicAdd(&h[v >> 17], 1);
    }
    __syncthreads();
    int myc = h[t];
    sc[t] = myc;
    __syncthreads();
    for (int off = 1; off < 256; off <<= 1) {
        int x = (t >= off) ? sc[t - off] : 0;
        __syncthreads();
        sc[t] += x;
        __syncthreads();
    }
    int ex = sc[t] - myc;
    lcur[t] = ex;
    int node = b * 256 + t;
    float dv = rsqrtf((float)myc + 1.0f);
    sdv[t] = dv;
    if (node < N) {
        cnt[node]    = myc;
        rowptr[node] = cb + ex;
        dinv[node]   = dv;
    }
    __syncthreads();
    for (int i = t; i < nB; i += 256) {
        unsigned v = buck[base + i];
        int dloc = v >> 17;
        int pos = cb + atomicAdd(&lcur[dloc], 1);
        ssrc[pos] = (int)(v & 0x1FFFFu);
    }
    // ---- scale Hs rows of this bucket by dinv (16 lanes x uint4 per row) ----
    int rbase = b * 256;
    int nrow  = min(256, N - rbase);
    int l16   = t & 15;
    for (int i = t >> 4; i < nrow; i += 16) {
        float d = sdv[i];
        uint4* rp = &Hq[(size_t)(rbase + i) * 16 + l16];
        uint4 u = *rp;
        uint4 o;
        {
            __hip_bfloat162 p;
            p = __float22bfloat162_rn(make_float2(__uint_as_float(u.x << 16) * d,
                                                  __uint_as_float(u.x & 0xffff0000u) * d));
            o.x = *(unsigned*)&p;
            p = __float22bfloat162_rn(make_float2(__uint_as_float(u.y << 16) * d,
                                                  __uint_as_float(u.y & 0xffff0000u) * d));
            o.y = *(unsigned*)&p;
            p = __float22bfloat162_rn(make_float2(__uint_as_float(u.z << 16) * d,
                                                  __uint_as_float(u.z & 0xffff0000u) * d));
            o.z = *(unsigned*)&p;
            p = __float22bfloat162_rn(make_float2(__uint_as_float(u.w << 16) * d,
                                                  __uint_as_float(u.w & 0xffff0000u) * d));
            o.w = *(unsigned*)&p;
        }
        *rp = o;
    }
}

__device__ inline short8 cvt8(float4 a, float4 b) {
    __hip_bfloat162 p0 = __float22bfloat162_rn(make_float2(a.x, a.y));
    __hip_bfloat162 p1 = __float22bfloat162_rn(make_float2(a.z, a.w));
    __hip_bfloat162 p2 = __float22bfloat162_rn(make_float2(b.x, b.y));
    __hip_bfloat162 p3 = __float22bfloat162_rn(make_float2(b.z, b.w));
    union { short8 s; __hip_bfloat162 h[4]; } u;
    u.h[0] = p0; u.h[1] = p1; u.h[2] = p2; u.h[3] = p3;
    return u.s;
}

// ---------------- MFMA GEMM body: Hs(bf16) = (op(X)@W + bias) [* dinv] ------
template <int K, bool BN, bool DINV>
__device__ void gemm_body(
    int bid,
    const float* __restrict__ X, const short* __restrict__ Wf,
    const float* __restrict__ bias, const float* __restrict__ dinv,
    const float* __restrict__ scale, const float* __restrict__ shift,
    __hip_bfloat16* __restrict__ Hs, int N)
{
    const int wave = threadIdx.x >> 6;
    const int lane = threadIdx.x & 63;
    const int l16  = lane & 15;
    const int q    = lane >> 4;            // 0..3
    const int r0   = bid * 128 + wave * 32;

    const int ra0 = min(r0 + l16, N - 1);
    const int ra1 = min(r0 + 16 + l16, N - 1);
    const float* pA0 = X + (size_t)ra0 * K + q * 8;
    const float* pA1 = X + (size_t)ra1 * K + q * 8;
    const short8* WF = (const short8*)Wf;

    floatx4 acc[2][8];
#pragma unroll
    for (int rt = 0; rt < 2; ++rt)
#pragma unroll
        for (int ct = 0; ct < 8; ++ct) { acc[rt][ct][0] = 0.f; acc[rt][ct][1] = 0.f; acc[rt][ct][2] = 0.f; acc[rt][ct][3] = 0.f; }

#pragma unroll
    for (int kc = 0; kc < K / 32; ++kc) {
        short8 b[8];
#pragma unroll
        for (int ct = 0; ct < 8; ++ct) b[ct] = WF[(kc * 8 + ct) * 64 + lane];

        float4 x00 = ntload4(pA0 + kc * 32);
        float4 x01 = ntload4(pA0 + kc * 32 + 4);
        float4 x10 = ntload4(pA1 + kc * 32);
        float4 x11 = ntload4(pA1 + kc * 32 + 4);
        if (BN) {
            float4 sc0 = *(const float4*)(scale + kc * 32 + q * 8);
            float4 sc1 = *(const float4*)(scale + kc * 32 + q * 8 + 4);
            float4 sh0 = *(const float4*)(shift + kc * 32 + q * 8);
            float4 sh1 = *(const float4*)(shift + kc * 32 + q * 8 + 4);
            x00.x = fmaxf(fmaf(x00.x, sc0.x, sh0.x), 0.f);
            x00.y = fmaxf(fmaf(x00.y, sc0.y, sh0.y), 0.f);
            x00.z = fmaxf(fmaf(x00.z, sc0.z, sh0.z), 0.f);
            x00.w = fmaxf(fmaf(x00.w, sc0.w, sh0.w), 0.f);
            x01.x = fmaxf(fmaf(x01.x, sc1.x, sh1.x), 0.f);
            x01.y = fmaxf(fmaf(x01.y, sc1.y, sh1.y), 0.f);
            x01.z = fmaxf(fmaf(x01.z, sc1.z, sh1.z), 0.f);
            x01.w = fmaxf(fmaf(x01.w, sc1.w, sh1.w), 0.f);
            x10.x = fmaxf(fmaf(x10.x, sc0.x, sh0.x), 0.f);
            x10.y = fmaxf(fmaf(x10.y, sc0.y, sh0.y), 0.f);
            x10.z = fmaxf(fmaf(x10.z, sc0.z, sh0.z), 0.f);
            x10.w = fmaxf(fmaf(x10.w, sc0.w, sh0.w), 0.f);
            x11.x = fmaxf(fmaf(x11.x, sc1.x, sh1.x), 0.f);
            x11.y = fmaxf(fmaf(x11.y, sc1.y, sh1.y), 0.f);
            x11.z = fmaxf(fmaf(x11.z, sc1.z, sh1.z), 0.f);
            x11.w = fmaxf(fmaf(x11.w, sc1.w, sh1.w), 0.f);
        }
        short8 a0 = cvt8(x00, x01);
        short8 a1 = cvt8(x10, x11);
#pragma unroll
        for (int ct = 0; ct < 8; ++ct) {
            acc[0][ct] = __builtin_amdgcn_mfma_f32_16x16x32_bf16(a0, b[ct], acc[0][ct], 0, 0, 0);
            acc[1][ct] = __builtin_amdgcn_mfma_f32_16x16x32_bf16(a1, b[ct], acc[1][ct], 0, 0, 0);
        }
    }

    float bb[8];
#pragma unroll
    for (int ct = 0; ct < 8; ++ct) bb[ct] = bias ? bias[ct * 16 + l16] : 0.f;

#pragma unroll
    for (int rt = 0; rt < 2; ++rt) {
        int rbase = r0 + rt * 16 + q * 4;
        float dv[4];
#pragma unroll
        for (int i = 0; i < 4; ++i) dv[i] = DINV ? dinv[min(rbase + i, N - 1)] : 1.f;
#pragma unroll
        for (int ct = 0; ct < 8; ++ct) {
#pragma unroll
            for (int i = 0; i < 4; ++i) {
                int row = rbase + i;
                if (row < N)
                    Hs[(size_t)row * 128 + ct * 16 + l16] =
                        __float2bfloat16(DINV ? (acc[rt][ct][i] + bb[ct]) * dv[i]
                                              : (acc[rt][ct][i] + bb[ct]));
            }
        }
    }
}

// ---------------- merged launch: gemm1 + bucket, interleaved mapping with
// ONE call site per body (r9 lesson: two gemm_body call sites -> VGPR 156,
// occupancy 8%, 130us; r6's single-call if/else compiled to VGPR 80).
// bids<2*BG: odd->bucket(bid/2), even->gemm(bid/2); rest->gemm(BG+bid-2BG).
// Bucket's memory/atomic work co-schedules with gemm MFMA from t=0.
__global__ __launch_bounds__(256) void gemm1_bucket_kernel(
    const float* __restrict__ X, const short* __restrict__ Wf,
    const float* __restrict__ bias,
    __hip_bfloat16* __restrict__ Hs, int N, int gemmGrid,
    const int* __restrict__ src, const int* __restrict__ dst,
    int* __restrict__ bcursor, unsigned* __restrict__ buck, int E, int nb,
    int bucketGrid)
{
    int bid  = (int)blockIdx.x;
    int twoB = 2 * bucketGrid;
    bool isBucket = (bid < twoB) && (bid & 1);
    int gidx = (bid < twoB) ? (bid >> 1) : (bucketGrid + (bid - twoB));
    if (isBucket)
        bucket_body(src, dst, bcursor, buck, E, nb, bucketGrid, bid >> 1);
    else
        gemm_body<256, false, false>(gidx, X, Wf, bias, nullptr, nullptr, nullptr, Hs, N);
}

__global__ __launch_bounds__(256) void mfma_gemm2_kernel(
    const float* __restrict__ X, const short* __restrict__ Wf,
    const float* __restrict__ dinv,
    const float* __restrict__ scale, const float* __restrict__ shift,
    __hip_bfloat16* __restrict__ Hs, int N)
{
    gemm_body<128, true, true>(blockIdx.x, X, Wf, nullptr, dinv, scale, shift, Hs, N);
}

// ---------------- gather-reduce aggregation over bf16 Hs (round-0 body) ------
// Settled at its floor (79.5us): survived ILP pipelining (r2 +4us),
// consumer-dinv (r5 +13us), fused-BN atomics (r1 +900us), split launches
// (r3 neutral), slice-major L2-affinity (r11: FETCH 193->79MB but dur 3x --
// 32B granule killed MLP). Row-major 256B rows, 16 uint4 loads in flight.
__device__ inline void accrow(uint4 u, float* a) {
    a[0] += __uint_as_float(u.x << 16);
    a[1] += __uint_as_float(u.x & 0xffff0000u);
    a[2] += __uint_as_float(u.y << 16);
    a[3] += __uint_as_float(u.y & 0xffff0000u);
    a[4] += __uint_as_float(u.z << 16);
    a[5] += __uint_as_float(u.z & 0xffff0000u);
    a[6] += __uint_as_float(u.w << 16);
    a[7] += __uint_as_float(u.w & 0xffff0000u);
}

__global__ __launch_bounds__(256) void agg_gather_kernel(
    const uint4* __restrict__ Hq, const int* __restrict__ rowptr,
    const int* __restrict__ cnt, const int* __restrict__ ssrc,
    const float* __restrict__ dinv, const float* __restrict__ bias,
    float* __restrict__ Out, int N)
{
    int node = blockIdx.x * 4 + (threadIdx.x >> 6);
    if (node >= N) return;
    int lane = threadIdx.x & 63;
    int q    = lane >> 4;     // quarter 0..3
    int l16  = lane & 15;

    float a0[8] = {0,0,0,0,0,0,0,0};
    float a1[8] = {0,0,0,0,0,0,0,0};
    float a2[8] = {0,0,0,0,0,0,0,0};
    float a3[8] = {0,0,0,0,0,0,0,0};

    if (q == 0) accrow(Hq[(size_t)node * 16 + l16], a0);   // self term

    int start = rowptr[node];
    int num   = cnt[node];
    int j = 0;
    for (; j + 16 <= num; j += 16) {
        int e = start + j + q;
        int s0 = ssrc[e];
        int s1 = ssrc[e + 4];
        int s2 = ssrc[e + 8];
        int s3 = ssrc[e + 12];
        uint4 u0 = Hq[(size_t)s0 * 16 + l16];
        uint4 u1 = Hq[(size_t)s1 * 16 + l16];
        uint4 u2 = Hq[(size_t)s2 * 16 + l16];
        uint4 u3 = Hq[(size_t)s3 * 16 + l16];
        accrow(u0, a0);
        accrow(u1, a1);
        accrow(u2, a2);
        accrow(u3, a3);
    }
    for (; j + 4 <= num; j += 4) {
        int s = ssrc[start + j + q];
        accrow(Hq[(size_t)s * 16 + l16], a0);
    }
    int rem = num - j;
    if (q < rem) {
        int s = ssrc[start + j + q];
        accrow(Hq[(size_t)s * 16 + l16], a1);
    }

#pragma unroll
    for (int i = 0; i < 8; ++i) {
        float v = a0[i] + a1[i] + a2[i] + a3[i];
        v += __shfl_xor(v, 16, 64);
        v += __shfl_xor(v, 32, 64);
        a0[i] = v;
    }

    if (q == 0) {
        float di = dinv[node];
        const float4* B4 = (const float4*)bias;
        float4 bb0 = B4[l16 * 2];
        float4 bb1 = B4[l16 * 2 + 1];
        float4 o0, o1;
        o0.x = fmaf(a0[0], di, bb0.x);
        o0.y = fmaf(a0[1], di, bb0.y);
        o0.z = fmaf(a0[2], di, bb0.z);
        o0.w = fmaf(a0[3], di, bb0.w);
        o1.x = fmaf(a0[4], di, bb1.x);
        o1.y = fmaf(a0[5], di, bb1.y);
        o1.z = fmaf(a0[6], di, bb1.z);
        o1.w = fmaf(a0[7], di, bb1.w);
        float4* O4 = (float4*)(Out + (size_t)node * 128 + l16 * 8);
        O4[0] = o0;
        O4[1] = o1;
    }
}

// ---------------- BN stats: partials + fused LAST-BLOCK finalize -------------
// The only viable in-kernel sync on this chip (r5 spin 93us, r7 spin 360us):
// nobody waits; the last arriving block does the finalize.
__global__ __launch_bounds__(256) void bn_stats_kernel(
    const float* __restrict__ A, float* __restrict__ partS, float* __restrict__ partQ,
    int N, int R,
    const float* __restrict__ gamma, const float* __restrict__ beta,
    float* __restrict__ scale, float* __restrict__ shift, int* __restrict__ ctr)
{
    int col4   = threadIdx.x & 31;
    int rowoff = threadIdx.x >> 5;
    int r0 = blockIdx.x * R;
    int r1 = min(r0 + R, N);
    float4 s = make_float4(0.f, 0.f, 0.f, 0.f);
    float4 qq = make_float4(0.f, 0.f, 0.f, 0.f);
#pragma unroll 4
    for (int r = r0 + rowoff; r < r1; r += 8) {
        float4 v = *(const float4*)&A[(size_t)r * 128 + col4 * 4];
        s.x += v.x; s.y += v.y; s.z += v.z; s.w += v.w;
        qq.x = fmaf(v.x, v.x, qq.x);
        qq.y = fmaf(v.y, v.y, qq.y);
        qq.z = fmaf(v.z, v.z, qq.z);
        qq.w = fmaf(v.w, v.w, qq.w);
    }
    __shared__ float4 ls[256], lq[256];
    ls[threadIdx.x] = s;
    lq[threadIdx.x] = qq;
    __syncthreads();
    if (threadIdx.x < 32) {
        float4 ts = ls[threadIdx.x], tq = lq[threadIdx.x];
#pragma unroll
        for (int k = 1; k < 8; ++k) {
            float4 xs = ls[k * 32 + threadIdx.x];
            float4 xq = lq[k * 32 + threadIdx.x];
            ts.x += xs.x; ts.y += xs.y; ts.z += xs.z; ts.w += xs.w;
            tq.x += xq.x; tq.y += xq.y; tq.z += xq.z; tq.w += xq.w;
        }
        *(float4*)&partS[(size_t)blockIdx.x * 128 + threadIdx.x * 4] = ts;
        *(float4*)&partQ[(size_t)blockIdx.x * 128 + threadIdx.x * 4] = tq;
    }
    __syncthreads();
    __shared__ int amLast;
    if (threadIdx.x == 0) {
        __threadfence();
        amLast = (atomicAdd(ctr, 1) == (int)gridDim.x - 1);
    }
    __syncthreads();
    if (!amLast) return;
    __threadfence();
    int c = threadIdx.x & 127;
    int h = threadIdx.x >> 7;
    float fs = 0.f, fq = 0.f;
    for (int b = h * 128; b < h * 128 + 128; ++b) {
        fs += partS[(size_t)b * 128 + c];
        fq += partQ[(size_t)b * 128 + c];
    }
    __shared__ float rs_[256], rq_[256];
    rs_[threadIdx.x] = fs;
    rq_[threadIdx.x] = fq;
    __syncthreads();
    if (threadIdx.x < 128) {
        float S = rs_[threadIdx.x] + rs_[threadIdx.x + 128];
        float Q = rq_[threadIdx.x] + rq_[threadIdx.x + 128];
        float m = S / (float)N;
        float v = Q / (float)N - m * m;
        float rs = rsqrtf(v + BN_EPS);
        float sc = gamma[c] * rs;
        scale[c] = sc;
        shift[c] = fmaf(-m, sc, beta[c]);
    }
}

// ---------------- final BN apply in-place on d_out (scale/shift form) --------
__global__ void bn_apply_kernel(float* __restrict__ A, const float* __restrict__ scale,
                                const float* __restrict__ shift, int N) {
    int i = blockIdx.x * blockDim.x + threadIdx.x;   // float4 index
    if (i >= N * 32) return;
    int c4 = i & 31;
    float4 v  = ((float4*)A)[i];
    float4 sc = ((const float4*)scale)[c4];
    float4 sh = ((const float4*)shift)[c4];
    v.x = fmaf(v.x, sc.x, sh.x);
    v.y = fmaf(v.y, sc.y, sh.y);
    v.z = fmaf(v.z, sc.z, sh.z);
    v.w = fmaf(v.w, sc.w, sh.w);
    ((float4*)A)[i] = v;
}

extern "C" void kernel_launch(void* const* d_in, const int* in_sizes, int n_in,
                              void* d_out, int out_size, void* d_ws, size_t ws_size,
                              hipStream_t stream) {
    const float* e_prev = (const float*)d_in[0];
    const int*   edges  = (const int*)d_in[1];
    const float* proj_W = (const float*)d_in[2];
    const float* proj_b = (const float*)d_in[3];
    const float* W1     = (const float*)d_in[4];
    const float* b1     = (const float*)d_in[5];
    const float* gamma1 = (const float*)d_in[6];
    const float* beta1  = (const float*)d_in[7];
    const float* W2     = (const float*)d_in[8];
    const float* b2     = (const float*)d_in[9];
    const float* gamma2 = (const float*)d_in[10];
    const float* beta2  = (const float*)d_in[11];
    float* out = (float*)d_out;

    const int N = in_sizes[0] / 256;
    const int E = in_sizes[1] / 2;
    const int* src = edges;
    const int* dst = edges + E;
    const int nb = (N + 255) >> 8;   // coarse buckets (391 for N=100k)
    const int R = (N + 255) / 256;   // rows per bn-stats block

    char* p = (char*)d_ws;
    const size_t NH = (size_t)N * 128;
    __hip_bfloat16* Hs = (__hip_bfloat16*)p;  p += NH * 2;
    unsigned* buck  = (unsigned*)p; p += (size_t)nb * CAP * 4;
    int* ssrc   = (int*)p;  p += (size_t)E * 4;
    int* cnt    = (int*)p;  p += (size_t)N * 4;
    int* rowptr = (int*)p;  p += (size_t)N * 4;
    float* dinv = (float*)p; p += (size_t)N * 4;
    int* bcursor = (int*)p; p += (size_t)(nb + 16) * 4;
    float* bc   = (float*)p; p += 128 * 4;
    float* stats = (float*)p; p += 1536 * 4;
    float* partS = (float*)p; p += 256 * 128 * 4;
    float* partQ = (float*)p; p += 256 * 128 * 4;
    __hip_bfloat16* Wf1 = (__hip_bfloat16*)p; p += 256 * 128 * 2;
    __hip_bfloat16* Wf2 = (__hip_bfloat16*)p; p += 128 * 128 * 2;
    float* scale1 = stats, *shift1 = stats + 128;
    float* scale2 = stats + 256, *shift2 = stats + 384;
    int* ctr1 = bcursor + nb + 8;
    int* ctr2 = bcursor + nb + 9;

    const int gemm_grid = (N + 127) / 128;
    const int bucket_grid = 512;

    // 1. prep (weights pack + bcursor/ctr init)
    prep_kernel<<<389, 128, 0, stream>>>(proj_W, W1, proj_b, W2, Wf1, Wf2, bc, bcursor, nb);
    // 2. gemm1 (unscaled Hs) + bucket, merged (interleaved map, 1 call site)
    gemm1_bucket_kernel<<<gemm_grid + bucket_grid, 256, 0, stream>>>(
        e_prev, (const short*)Wf1, bc, Hs, N, gemm_grid,
        src, dst, bcursor, buck, E, nb, bucket_grid);
    // 3. CSR build + in-place dinv scaling of Hs
    csr_kernel<<<nb, 256, 0, stream>>>(buck, bcursor, cnt, rowptr, dinv, ssrc,
                                       (uint4*)Hs, N);
    // 4. layer-1 aggregation
    agg_gather_kernel<<<(N + 3) / 4, 256, 0, stream>>>(
        (const uint4*)Hs, rowptr, cnt, ssrc, dinv, b1, out, N);
    // 5. BN1 stats (last-block finalize -> scale1/shift1)
    bn_stats_kernel<<<256, 256, 0, stream>>>(out, partS, partQ, N, R,
                                             gamma1, beta1, scale1, shift1, ctr1);
    // 6. layer-2 GEMM (BN1+relu on the fly, dinv epilogue)
    mfma_gemm2_kernel<<<gemm_grid, 256, 0, stream>>>(
        out, (const short*)Wf2, dinv, scale1, shift1, Hs, N);
    // 7. layer-2 aggregation
    agg_gather_kernel<<<(N + 3) / 4, 256, 0, stream>>>(
        (const uint4*)Hs, rowptr, cnt, ssrc, dinv, b2, out, N);
    // 8. BN2 stats (last-block finalize -> scale2/shift2)
    bn_stats_kernel<<<256, 256, 0, stream>>>(out, partS, partQ, N, R,
                                             gamma2, beta2, scale2, shift2, ctr2);
    // 9. BN2 apply
    bn_apply_kernel<<<(N * 32 + 255) / 256, 256, 0, stream>>>(out, scale2, shift2, N);
}